// Round 1
// 302.358 us; speedup vs baseline: 1.2012x; 1.2012x over previous
//
#include <hip/hip_runtime.h>
#include <hip/hip_bf16.h>

#define D_IN  2048
#define D_OUT 2048
#define RNK   64
#define NE    16
#define KTOT  3072   // D_IN + NE*RNK

typedef __attribute__((ext_vector_type(8))) short bf16x8;
typedef __attribute__((ext_vector_type(4))) float f32x4;

__device__ __forceinline__ void async_ld16(const void* g, void* l) {
    __builtin_amdgcn_global_load_lds(
        (const __attribute__((address_space(1))) void*)g,
        (__attribute__((address_space(3))) void*)l,
        16, 0, 0);
}

// ---------------------------------------------------------------------------
// K1: merged weight prep.
//  blocks [0,2048):   Wc row n = [ W_base | B' ], B'[n][e*64+r] = B[e][n][r]
//  blocks [2048,2112): Ab row r = bf16(A[r])  (parked in d_out)
// ---------------------------------------------------------------------------
__global__ __launch_bounds__(384) void castwa_kernel(
    const float* __restrict__ Wb, const float* __restrict__ Bm,
    const float* __restrict__ A,
    __hip_bfloat16* __restrict__ Wc, __hip_bfloat16* __restrict__ Ab)
{
    const int c = threadIdx.x * 8;
    const float* src;
    __hip_bfloat16* dst;
    if (blockIdx.x < D_OUT) {
        const int n = blockIdx.x;
        if (c < D_IN) {
            src = Wb + (size_t)n * D_IN + c;
        } else {
            const int j = c - D_IN;
            const int e = j >> 6, r = j & 63;
            src = Bm + ((size_t)e * D_OUT + n) * RNK + r;
        }
        dst = Wc + (size_t)n * KTOT + c;
    } else {
        if (c >= D_IN) return;
        const int r = blockIdx.x - D_OUT;
        src = A + (size_t)r * D_IN + c;
        dst = Ab + (size_t)r * D_IN + c;
    }
    const float4 a = *(const float4*)src;
    const float4 b = *(const float4*)(src + 4);
    const float vv[8] = {a.x, a.y, a.z, a.w, b.x, b.y, b.z, b.w};
    union { bf16x8 v; __hip_bfloat16 h[8]; } u;
#pragma unroll
    for (int q = 0; q < 8; ++q) u.h[q] = __float2bfloat16(vv[q]);
    *(bf16x8*)dst = u.v;
}

// ---------------------------------------------------------------------------
// K2: prep — bf16(x) emit + fp32 router logits + softmax/top-k -> wfin.
// v2: W_router K-chunks staged into LDS once per BLOCK (double-buffered
// async global_load_lds) instead of every wave re-reading all 128 KB from
// global. Kills the L2 hot-line contention that made v1 latency-bound
// (123 us at 13% VALUBusy). Router math stays fp32 so top-k selection
// matches the reference bit-exactly.
// ---------------------------------------------------------------------------
__global__ __launch_bounds__(256) void prep_kernel(
    const float* __restrict__ x, const float* __restrict__ Wr,
    const int* __restrict__ topk_p, __hip_bfloat16* __restrict__ Xc,
    float* __restrict__ wfin)
{
    __shared__ __align__(16) float wr_lds[2][NE * 256];   // 2 x 16 KB
    const int tid = threadIdx.x;
    const int wave = tid >> 6, lane = tid & 63;
    const int t0 = blockIdx.x * 8 + wave * 2;   // 2 tokens per wave

    float acc[NE][2];
#pragma unroll
    for (int e = 0; e < NE; ++e) { acc[e][0] = 0.f; acc[e][1] = 0.f; }

    const float4* x4 = (const float4*)x;

    // Stage Wr rows for K-chunk i into buffer buf.
    // Wave w stages rows [4w, 4w+4); one async_ld16 covers one 256-float row
    // (64 lanes x 16 B), LDS dst = uniform base + lane*16.
    auto stage = [&](int buf, int i) {
#pragma unroll
        for (int j = 0; j < 4; ++j) {
            const int r = wave * 4 + j;
            async_ld16(Wr + (size_t)r * D_IN + i * 256 + lane * 4,
                       (void*)&wr_lds[buf][r * 256]);
        }
    };

    stage(0, 0);
    __syncthreads();                             // chunk 0 staged (vmcnt drained)

#pragma unroll
    for (int i = 0; i < 8; ++i) {                // K chunks of 256 floats
        if (i < 7) stage((i + 1) & 1, i + 1);    // async prefetch next chunk

        float4 xv[2];
#pragma unroll
        for (int t = 0; t < 2; ++t) {
            xv[t] = x4[(size_t)(t0 + t) * 512 + i * 64 + lane];
            union { short4 v; __hip_bfloat16 h[4]; } u;
            u.h[0] = __float2bfloat16(xv[t].x); u.h[1] = __float2bfloat16(xv[t].y);
            u.h[2] = __float2bfloat16(xv[t].z); u.h[3] = __float2bfloat16(xv[t].w);
            *(short4*)(Xc + (size_t)(t0 + t) * KTOT + (i * 64 + lane) * 4) = u.v;
        }

        const float4* wr4 = (const float4*)wr_lds[i & 1];
#pragma unroll
        for (int e = 0; e < NE; ++e) {
            const float4 wv = wr4[e * 64 + lane];
#pragma unroll
            for (int t = 0; t < 2; ++t)
                acc[e][t] += xv[t].x * wv.x + xv[t].y * wv.y
                           + xv[t].z * wv.z + xv[t].w * wv.w;
        }
        __syncthreads();   // drains prefetch + guards buffer reuse
    }

#pragma unroll
    for (int off = 32; off; off >>= 1)
#pragma unroll
        for (int e = 0; e < NE; ++e)
#pragma unroll
            for (int t = 0; t < 2; ++t)
                acc[e][t] += __shfl_xor(acc[e][t], off, 64);

    if (lane < 2) {
        const int tt = lane;
        const int k = topk_p[0];
        float m = -1e30f;
#pragma unroll
        for (int e = 0; e < NE; ++e) m = fmaxf(m, acc[e][tt]);
        float w[NE]; float ssum = 0.f;
#pragma unroll
        for (int e = 0; e < NE; ++e) { w[e] = __expf(acc[e][tt] - m); ssum += w[e]; }
        const float inv = 1.f / ssum;
#pragma unroll
        for (int e = 0; e < NE; ++e) w[e] *= inv;
        float* wfout = wfin + (size_t)(t0 + tt) * NE;
        if (k > 0 && k < NE) {
            int chosen[NE];
#pragma unroll
            for (int e = 0; e < NE; ++e) chosen[e] = 0;
            float ksum = 0.f;
            for (int it = 0; it < k; ++it) {
                int bi = 0; float bv = -1.f;
                for (int e = 0; e < NE; ++e)
                    if (!chosen[e] && w[e] > bv) { bv = w[e]; bi = e; }
                chosen[bi] = 1; ksum += bv;
            }
            const float rinv = 1.f / (ksum + 1e-6f);
            for (int e = 0; e < NE; ++e) wfout[e] = chosen[e] ? w[e] * rinv : 0.f;
        } else {
            for (int e = 0; e < NE; ++e) wfout[e] = w[e];
        }
    }
}

// ---------------------------------------------------------------------------
// K3: rh+combine fused, 16-token tiles (512 blocks = 2/CU for latency hiding).
// RH = bf16x @ Ab^T (K=2048) via MFMA, XOR-swizzled LDS; then
// t[e*64+r] = wfin[e]*rh[r] written with coalesced bf16x8 stores.
// ---------------------------------------------------------------------------
__global__ __launch_bounds__(256) void rhfused_kernel(
    __hip_bfloat16* Xc, const __hip_bfloat16* __restrict__ Ab,
    const float* __restrict__ wfin)
{
    __shared__ __align__(16) char smem[10240 + 1024];
    __hip_bfloat16* lds_a = (__hip_bfloat16*)smem;            // 16x64 bf16 = 2KB
    __hip_bfloat16* lds_b = (__hip_bfloat16*)(smem + 2048);   // 64x64 bf16 = 8KB
    const int tid = threadIdx.x;
    const int wave = tid >> 6, lane = tid & 63;
    const int qm = lane & 15, quad = lane >> 4;
    const int ar = lane >> 3;
    const int ac = ((lane & 7) ^ ar) * 8;      // XOR-swizzled source granule
    const int t0b = blockIdx.x * 16;

    f32x4 acc = {};

    for (int k0 = 0; k0 < D_IN; k0 += 64) {
        if (wave < 2) {   // A tile: 16 token rows
            const __hip_bfloat16* ga =
                Xc + (size_t)(t0b + wave * 8 + ar) * KTOT + k0 + ac;
            async_ld16(ga, (void*)&lds_a[wave * 512]);
        }
#pragma unroll
        for (int j = 0; j < 2; ++j) {          // B tile: 64 A-rows
            const __hip_bfloat16* gb =
                Ab + (size_t)(wave * 16 + j * 8 + ar) * D_IN + k0 + ac;
            async_ld16(gb, (void*)&lds_b[(wave * 2 + j) * 512]);
        }
        __syncthreads();
#pragma unroll
        for (int kk = 0; kk < 64; kk += 32) {
            const int cg = (kk >> 3) + quad;
            const int sw = (cg ^ (qm & 7)) * 8;
            bf16x8 af = *(const bf16x8*)&lds_a[qm * 64 + sw];
            bf16x8 bfr = *(const bf16x8*)&lds_b[(wave * 16 + qm) * 64 + sw];
            acc = __builtin_amdgcn_mfma_f32_16x16x32_bf16(af, bfr, acc, 0, 0, 0);
        }
        __syncthreads();
    }

    float* rh = (float*)smem;                       // 16x64 f32 = 4KB
    float* wf = (float*)(smem + 4096);              // 16x16 f32 = 1KB
#pragma unroll
    for (int r = 0; r < 4; ++r)
        rh[(quad * 4 + r) * 64 + wave * 16 + qm] = acc[r];   // token row, RH col
    if (tid < 64) {
        const int t = tid >> 2, part = tid & 3;
        ((float4*)wf)[t * 4 + part] =
            ((const float4*)(wfin + (size_t)(t0b + t) * NE))[part];
    }
    __syncthreads();

#pragma unroll
    for (int it = 0; it < 8; ++it) {
        const int s = it * 256 + tid;      // bf16x8 store index
        const int t = s >> 7;              // 128 chunks per token
        const int chunk = s & 127;
        const int e = chunk >> 3, r0 = (chunk & 7) * 8;
        const float w = wf[t * 16 + e];
        union { bf16x8 v; __hip_bfloat16 h[8]; } u;
#pragma unroll
        for (int q = 0; q < 8; ++q)
            u.h[q] = __float2bfloat16(w * rh[t * 64 + r0 + q]);
        *(bf16x8*)(Xc + (size_t)(t0b + t) * KTOT + D_IN + chunk * 8) = u.v;
    }
}

// ---------------------------------------------------------------------------
// K4: main GEMM C = Xc @ Wc^T + bias (M=8192, N=2048, K=3072).
// 128x128 tile, XOR-swizzled LDS, bm-fastest grid (R2's empirically best
// fetch: 99 MB vs 209 MB for bn-fastest/supertile), hoisted staging pointers.
// ---------------------------------------------------------------------------
__global__ __launch_bounds__(256) void gemm_kernel(
    const __hip_bfloat16* __restrict__ Am,
    const __hip_bfloat16* __restrict__ Bm,
    const float* __restrict__ bias,
    float* __restrict__ C, int M, int N)
{
    __shared__ __hip_bfloat16 lds_a[128 * 64];
    __shared__ __hip_bfloat16 lds_b[128 * 64];
    const int tid = threadIdx.x;
    const int wave = tid >> 6, lane = tid & 63;
    const int bm = blockIdx.x, bn = blockIdx.y;    // bm fastest
    const int qm = lane & 15, quad = lane >> 4;
    const int ar = lane >> 3;
    const int ac = ((lane & 7) ^ ar) * 8;          // XOR-swizzled source granule

    f32x4 acc[4][4] = {};
    const int wm = (wave >> 1) * 64, wn = (wave & 1) * 64;

    const __hip_bfloat16* ga[4];
    const __hip_bfloat16* gb[4];
#pragma unroll
    for (int j = 0; j < 4; ++j) {
        ga[j] = Am + (size_t)(bm * 128 + wave * 32 + j * 8 + ar) * KTOT + ac;
        gb[j] = Bm + (size_t)(bn * 128 + wave * 32 + j * 8 + ar) * KTOT + ac;
    }

    for (int k0 = 0; k0 < KTOT; k0 += 64) {
#pragma unroll
        for (int j = 0; j < 4; ++j) {
            async_ld16(ga[j], (void*)&lds_a[(wave * 4 + j) * 512]);
            async_ld16(gb[j], (void*)&lds_b[(wave * 4 + j) * 512]);
            ga[j] += 64; gb[j] += 64;
        }
        __syncthreads();

#pragma unroll
        for (int kk = 0; kk < 64; kk += 32) {
            const int cg = (kk >> 3) + quad;
            const int sw = (cg ^ (qm & 7)) * 8;
            bf16x8 af[4], bfr[4];
#pragma unroll
            for (int i = 0; i < 4; ++i)
                af[i] = *(const bf16x8*)&lds_a[(wm + i * 16 + qm) * 64 + sw];
#pragma unroll
            for (int j = 0; j < 4; ++j)
                bfr[j] = *(const bf16x8*)&lds_b[(wn + j * 16 + qm) * 64 + sw];
#pragma unroll
            for (int i = 0; i < 4; ++i)
#pragma unroll
                for (int j = 0; j < 4; ++j)
                    acc[i][j] = __builtin_amdgcn_mfma_f32_16x16x32_bf16(
                        af[i], bfr[j], acc[i][j], 0, 0, 0);
        }
        __syncthreads();
    }

    const size_t row0 = (size_t)bm * 128 + wm;
    const int col0 = bn * 128 + wn;
#pragma unroll
    for (int j = 0; j < 4; ++j) {
        const int col = col0 + j * 16 + qm;
        const float bb = bias[col];
#pragma unroll
        for (int i = 0; i < 4; ++i) {
#pragma unroll
            for (int r = 0; r < 4; ++r) {
                const size_t row = row0 + i * 16 + quad * 4 + r;
                C[row * (size_t)N + col] = acc[i][j][r] + bb;
            }
        }
    }
}

extern "C" void kernel_launch(void* const* d_in, const int* in_sizes, int n_in,
                              void* d_out, int out_size, void* d_ws, size_t ws_size,
                              hipStream_t stream) {
    const float* x    = (const float*)d_in[0];
    const float* Wb   = (const float*)d_in[1];
    const float* bb   = (const float*)d_in[2];
    const float* A    = (const float*)d_in[3];
    const float* Bm   = (const float*)d_in[4];
    const float* Wr   = (const float*)d_in[5];
    const int*   topk = (const int*)d_in[6];
    float* out = (float*)d_out;
    const int T = in_sizes[0] / D_IN;   // 8192 tokens

    __hip_bfloat16* Xc = (__hip_bfloat16*)d_ws;                                 // T*KTOT bf16 (48MB)
    __hip_bfloat16* Wc = (__hip_bfloat16*)((char*)d_ws + (size_t)T * KTOT * 2); // D_OUT*KTOT bf16 (12MB)
    // Parked in d_out (fully overwritten by the final GEMM):
    __hip_bfloat16* Ab = (__hip_bfloat16*)d_out;              // 256 KB at front
    float* wfin = (float*)d_out + 8 * 1024 * 1024;            // 512 KB at +32MB

    castwa_kernel<<<D_OUT + RNK, 384, 0, stream>>>(Wb, Bm, A, Wc, Ab);
    prep_kernel<<<T / 8, 256, 0, stream>>>(x, Wr, topk, Xc, wfin);
    rhfused_kernel<<<T / 16, 256, 0, stream>>>(Xc, Ab, wfin);
    gemm_kernel<<<dim3(T / 128, D_OUT / 128), 256, 0, stream>>>(Xc, Wc, bb, out, T, D_OUT);
}